// Round 12
// baseline (269.030 us; speedup 1.0000x reference)
//
#include <hip/hip_runtime.h>
#include <cstdint>
#include <cstddef>

#define NB    32          // batches
#define SEQ   1024        // sequence length
#define DIN   256
#define HID   512
#define MTOT  32768       // NB*SEQ

typedef _Float16 half_t;
typedef _Float16 half8  __attribute__((ext_vector_type(8)));
typedef _Float16 half4v __attribute__((ext_vector_type(4)));
typedef float    f32x4  __attribute__((ext_vector_type(4)));

typedef __attribute__((address_space(1))) const void* gas_ptr;
typedef __attribute__((address_space(3))) void*       las_ptr;

// Register model (r8/r10/r11): reported VGPR_Count excludes MFMA accumulators;
// unified budget/wave = 512 / (waves per SIMD). acc[2][8]=64-reg tiles fit
// (256,3)=3 blocks/CU (se_k r11: verified, no spill). acc[4][8]=128 needs (256,2).
// r12: pv_k -> 128x128 tile + 4 M-split waves + (256,3); gemm_k -> (256,3)
// (acc 64 + arch 56 ~ 120 <= 170 budget).
// T2 swizzle: on pv_k/gemm_k (conflicts->0); NOT on se_k (permuted source broke
// run-length coalescing in its L2-request-bound staging: r9 A/B 72.7 vs 55.3).

// ---------------- f32 -> f16 convert ----------------
__global__ void cvt_kernel(const float* __restrict__ src, half_t* __restrict__ dst, int n4) {
    int i = blockIdx.x * blockDim.x + threadIdx.x;
    if (i < n4) {
        f32x4 v = ((const f32x4*)src)[i];
        half4v h;
        h[0] = (half_t)v[0]; h[1] = (half_t)v[1]; h[2] = (half_t)v[2]; h[3] = (half_t)v[3];
        ((half4v*)dst)[i] = h;
    }
}

// all 4 weight matrices are HID*DIN == DIN*HID elements; blockIdx.y selects
__global__ void cvt4_kernel(const float* __restrict__ s0, const float* __restrict__ s1,
                            const float* __restrict__ s2, const float* __restrict__ s3,
                            half_t* __restrict__ d0, half_t* __restrict__ d1,
                            half_t* __restrict__ d2, half_t* __restrict__ d3, int n4) {
    int y = blockIdx.y;
    const float* s = y == 0 ? s0 : y == 1 ? s1 : y == 2 ? s2 : s3;
    half_t*      d = y == 0 ? d0 : y == 1 ? d1 : y == 2 ? d2 : d3;
    int i = blockIdx.x * blockDim.x + threadIdx.x;
    if (i < n4) {
        f32x4 v = ((const f32x4*)s)[i];
        half4v h;
        h[0] = (half_t)v[0]; h[1] = (half_t)v[1]; h[2] = (half_t)v[2]; h[3] = (half_t)v[3];
        ((half4v*)d)[i] = h;
    }
}

__global__ void pack_bias(const float* __restrict__ bv, const float* __restrict__ bk,
                          const float* __restrict__ bq, float* __restrict__ dst) {
    int t = threadIdx.x;
    if (t < HID) {
        dst[t]         = bv[t];
        dst[HID + t]   = bk[t];
        dst[2*HID + t] = bq[t];
    }
}

// ---------------- generic GEMM (projections), 128x128 tile ----------------
// C[m][n] = sum_k A[m][k] * B[n][k]
// K-loop unrolled x2 (two 32-wide sub-buffers, one sync pair per 64-wide step).
// T2 swizzle: source kchunk ^((c>>3)&3), read slot quad^((lanen>>1)&3).
// (256,3): acc 64 + arch ~56 = ~120 <= 170-reg budget -> 3 blocks/CU (LDS 32KB).
// MODE 0: QKV proj. bias+relu, f16 out. z=0 -> transposed into out2 (vT[b][h][m]); z=1,2 -> row-major.
// MODE 3: out proj. f32 out, bias+relu.
template<int MODE>
__global__ __launch_bounds__(256, 3) void gemm_k(
    const half_t* __restrict__ A, long lda, long a_bs,
    const half_t* __restrict__ Bw, long ldb, long b_bs,
    void* __restrict__ Out, long ldo, long o_bs,
    const float* __restrict__ bias,
    int Kdim, half_t* __restrict__ out2)
{
    __shared__ alignas(16) half_t As[2][128 * 32];
    __shared__ alignas(16) half_t Bs[2][128 * 32];

    const int t    = threadIdx.x;
    const int lane = t & 63;
    const int wave = t >> 6;
    const int wm   = wave >> 1;
    const int wn   = wave & 1;
    const int lanen = lane & 15;
    const int quad  = lane >> 4;
    const int sl    = quad ^ ((lanen >> 1) & 3);   // swizzled read slot
    const int z     = blockIdx.z;
    const long m0 = (long)blockIdx.x * 128;
    const long n0 = (long)blockIdx.y * 128;

    const half_t* Ab = A  + (long)z * a_bs;
    const half_t* Bb = Bw + (long)z * b_bs;

    f32x4 acc[4][4];
#pragma unroll
    for (int i = 0; i < 4; i++)
#pragma unroll
        for (int j = 0; j < 4; j++)
            acc[i][j] = f32x4{0.f, 0.f, 0.f, 0.f};

    const int c0 = t, c1 = t + 256;
    const int r0 = c0 >> 2, kc0 = (c0 & 3) ^ ((c0 >> 3) & 3);   // pre-swizzled source slot
    const int r1 = c1 >> 2, kc1 = (c1 & 3) ^ ((c1 >> 3) & 3);

    const half_t* gA0 = Ab + (m0 + r0) * lda + kc0 * 8;
    const half_t* gA1 = Ab + (m0 + r1) * lda + kc1 * 8;
    const half_t* gB0 = Bb + (n0 + r0) * ldb + kc0 * 8;
    const half_t* gB1 = Bb + (n0 + r1) * ldb + kc1 * 8;
    const int lA0 = c0 * 8, lA1 = c1 * 8;
    const int lB0 = c0 * 8, lB1 = c1 * 8;

    int aoff[4], boff[4];
#pragma unroll
    for (int i = 0; i < 4; i++) aoff[i] = (wm * 64 + i * 16 + lanen) * 32 + sl * 8;
#pragma unroll
    for (int j = 0; j < 4; j++) boff[j] = (wn * 64 + j * 16 + lanen) * 32 + sl * 8;

    for (int k0 = 0; k0 < Kdim; k0 += 64) {
#pragma unroll
        for (int sub = 0; sub < 2; sub++) {
            const int ks = k0 + sub * 32;
            __builtin_amdgcn_global_load_lds((gas_ptr)(gA0 + ks), (las_ptr)&As[sub][lA0], 16, 0, 0);
            __builtin_amdgcn_global_load_lds((gas_ptr)(gA1 + ks), (las_ptr)&As[sub][lA1], 16, 0, 0);
            __builtin_amdgcn_global_load_lds((gas_ptr)(gB0 + ks), (las_ptr)&Bs[sub][lB0], 16, 0, 0);
            __builtin_amdgcn_global_load_lds((gas_ptr)(gB1 + ks), (las_ptr)&Bs[sub][lB1], 16, 0, 0);
        }
        __syncthreads();

        {
            half8 af[4], bf[4];
#pragma unroll
            for (int i = 0; i < 4; i++) af[i] = *(const half8*)&As[0][aoff[i]];
#pragma unroll
            for (int j = 0; j < 4; j++) bf[j] = *(const half8*)&Bs[0][boff[j]];
#pragma unroll
            for (int i = 0; i < 4; i++)
#pragma unroll
                for (int j = 0; j < 4; j++)
                    acc[i][j] = __builtin_amdgcn_mfma_f32_16x16x32_f16(af[i], bf[j], acc[i][j], 0, 0, 0);
        }
        {
            half8 af[4], bf[4];
#pragma unroll
            for (int i = 0; i < 4; i++) af[i] = *(const half8*)&As[1][aoff[i]];
#pragma unroll
            for (int j = 0; j < 4; j++) bf[j] = *(const half8*)&Bs[1][boff[j]];
#pragma unroll
            for (int i = 0; i < 4; i++)
#pragma unroll
                for (int j = 0; j < 4; j++)
                    acc[i][j] = __builtin_amdgcn_mfma_f32_16x16x32_f16(af[i], bf[j], acc[i][j], 0, 0, 0);
        }
        __syncthreads();
    }

    // C/D layout: col = lane&15, row = quad*4 + reg
#pragma unroll
    for (int i = 0; i < 4; i++) {
        long mrow = m0 + wm * 64 + i * 16 + quad * 4;
#pragma unroll
        for (int j = 0; j < 4; j++) {
            long gn = n0 + wn * 64 + j * 16 + lanen;
            f32x4 v = acc[i][j];
            if (MODE == 0) {
                float bb = bias[z * HID + gn];
                half_t h0 = (half_t)fmaxf(v[0] + bb, 0.f);
                half_t h1 = (half_t)fmaxf(v[1] + bb, 0.f);
                half_t h2 = (half_t)fmaxf(v[2] + bb, 0.f);
                half_t h3 = (half_t)fmaxf(v[3] + bb, 0.f);
                if (z == 0) {
                    long bidx = mrow >> 10;
                    long pos  = mrow & 1023;
                    half4v pk; pk[0] = h0; pk[1] = h1; pk[2] = h2; pk[3] = h3;
                    *(half4v*)(out2 + ((bidx * HID + gn) << 10) + pos) = pk;
                } else {
                    half_t* o = (half_t*)Out + (long)(z - 1) * o_bs;
                    o[(mrow + 0) * ldo + gn] = h0;
                    o[(mrow + 1) * ldo + gn] = h1;
                    o[(mrow + 2) * ldo + gn] = h2;
                    o[(mrow + 3) * ldo + gn] = h3;
                }
            } else {
                float* o = (float*)Out;
                float bb = bias[gn];
#pragma unroll
                for (int r = 0; r < 4; r++) o[(mrow + r) * ldo + gn] = fmaxf(v[r] + bb, 0.f);
            }
        }
    }
}

// ---------------- S = q k^T with fused exp, 128x128 tile, 4 M-split waves ----------------
// Each wave owns 32 m-rows x ALL 128 n-cols (acc[2][8] = 64 acc-regs) -> (256,3),
// 3 blocks/CU. n-tile == stats block -> per-wave stats, kb = by. Linear staging
// source (no T2: r9). SWZ=1: batch pinned to XCD (L2-resident Q/K).
template<int SWZ>
__global__ __launch_bounds__(256, 3) void se_k(
    const half_t* __restrict__ Q, const half_t* __restrict__ K,
    half_t* __restrict__ E, float* __restrict__ Mstat, float* __restrict__ Lstat)
{
    __shared__ alignas(16) half_t As[2][128 * 32];
    __shared__ alignas(16) half_t Bs[2][128 * 32];

    const int t    = threadIdx.x;
    const int lane = t & 63;
    const int wm   = t >> 6;        // 0..3: wave's 32-row m-group
    const int lanen = lane & 15;
    const int quad  = lane >> 4;

    int bx, by, z;
    if (SWZ) {
        const int wgid = blockIdx.x;
        const int c    = wgid & 7;        // XCD
        const int tmp  = wgid >> 3;
        const int tile = tmp & 63;        // 64 tiles (8m x 8n) per batch
        z  = c + 8 * (tmp >> 6);
        bx = tile & 7;
        by = tile >> 3;
    } else {
        bx = blockIdx.x; by = blockIdx.y; z = blockIdx.z;
    }
    const long m0 = (long)bx * 128;
    const long n0 = (long)by * 128;

    const half_t* Ab = Q + (long)z * SEQ * HID;
    const half_t* Bb = K + (long)z * SEQ * HID;

    f32x4 acc[2][8];
#pragma unroll
    for (int i = 0; i < 2; i++)
#pragma unroll
        for (int j = 0; j < 8; j++)
            acc[i][j] = f32x4{0.f, 0.f, 0.f, 0.f};

    // A: 512 chunks (2/thread), B: 512 chunks (2/thread); chunk c -> row c>>2, kchunk c&3
    const half_t* gA[2]; int lA[2];
    const half_t* gB[2]; int lB[2];
#pragma unroll
    for (int s = 0; s < 2; s++) {
        int c = t + 256 * s;
        gA[s] = Ab + (m0 + (c >> 2)) * HID + (c & 3) * 8;
        gB[s] = Bb + (n0 + (c >> 2)) * HID + (c & 3) * 8;
        lA[s] = c * 8;
        lB[s] = c * 8;
    }

    int aoff[2], boff[8];
#pragma unroll
    for (int i = 0; i < 2; i++) aoff[i] = (wm * 32 + i * 16 + lanen) * 32 + quad * 8;
#pragma unroll
    for (int j = 0; j < 8; j++) boff[j] = (j * 16 + lanen) * 32 + quad * 8;

    for (int k0 = 0; k0 < HID; k0 += 64) {
#pragma unroll
        for (int sub = 0; sub < 2; sub++) {
            const int ks = k0 + sub * 32;
#pragma unroll
            for (int s = 0; s < 2; s++) {
                __builtin_amdgcn_global_load_lds((gas_ptr)(gA[s] + ks), (las_ptr)&As[sub][lA[s]], 16, 0, 0);
                __builtin_amdgcn_global_load_lds((gas_ptr)(gB[s] + ks), (las_ptr)&Bs[sub][lB[s]], 16, 0, 0);
            }
        }
        __syncthreads();

#pragma unroll
        for (int sub = 0; sub < 2; sub++) {
            half8 af0 = *(const half8*)&As[sub][aoff[0]];
            half8 af1 = *(const half8*)&As[sub][aoff[1]];
#pragma unroll
            for (int j = 0; j < 8; j++) {
                half8 bf = *(const half8*)&Bs[sub][boff[j]];
                acc[0][j] = __builtin_amdgcn_mfma_f32_16x16x32_f16(af0, bf, acc[0][j], 0, 0, 0);
                acc[1][j] = __builtin_amdgcn_mfma_f32_16x16x32_f16(af1, bf, acc[1][j], 0, 0, 0);
            }
        }
        __syncthreads();
    }

    // ---- epilogue: per-wave row max over the full 128-col stats block ----
    float mf[2][4];
#pragma unroll
    for (int i = 0; i < 2; i++)
#pragma unroll
        for (int r = 0; r < 4; r++) {
            float v = acc[i][0][r];
#pragma unroll
            for (int j = 1; j < 8; j++) v = fmaxf(v, acc[i][j][r]);
#pragma unroll
            for (int off = 8; off > 0; off >>= 1)
                v = fmaxf(v, __shfl_xor(v, off, 64));
            mf[i][r] = v;
        }

    // ---- exp + row partial sums + E store ----
    half_t* Eb = E + (long)z * SEQ * SEQ;
    float rs[2][4];
#pragma unroll
    for (int i = 0; i < 2; i++)
#pragma unroll
        for (int r = 0; r < 4; r++) rs[i][r] = 0.f;
#pragma unroll
    for (int i = 0; i < 2; i++) {
        long mrow = m0 + wm * 32 + i * 16 + quad * 4;
#pragma unroll
        for (int j = 0; j < 8; j++) {
            long gn = n0 + j * 16 + lanen;
#pragma unroll
            for (int r = 0; r < 4; r++) {
                float e = __expf(acc[i][j][r] - mf[i][r]);
                rs[i][r] += e;
                Eb[(mrow + r) * SEQ + gn] = (half_t)e;
            }
        }
    }
#pragma unroll
    for (int i = 0; i < 2; i++)
#pragma unroll
        for (int r = 0; r < 4; r++) {
            float v = rs[i][r];
#pragma unroll
            for (int off = 8; off > 0; off >>= 1)
                v += __shfl_xor(v, off, 64);
            rs[i][r] = v;
        }

    // stats: kb = by (n-tile == stats block); rows are wave-private -> no conflicts
    if (lanen == 0) {
        long base = ((long)z * 8 + by) * SEQ + m0 + wm * 32;
#pragma unroll
        for (int i = 0; i < 2; i++)
#pragma unroll
            for (int r = 0; r < 4; r++) {
                Mstat[base + i * 16 + quad * 4 + r] = mf[i][r];
                Lstat[base + i * 16 + quad * 4 + r] = rs[i][r];
            }
    }
}

// ---------------- O = P vT, 128x128 tile, 4 M-split waves ----------------
// Each wave owns 32 m-rows x ALL 128 h-cols (acc[2][8] = 64 acc-regs) -> (256,3),
// 3 blocks/CU (was 128x256 @ 2). Stat-merge rescale + normalize unchanged.
// T2 swizzle kept. SWZ=1: batch pinned to XCD (E+vT L2-resident).
template<int SWZ>
__global__ __launch_bounds__(256, 3) void pv_k(
    const half_t* __restrict__ E, const half_t* __restrict__ vT,
    const float* __restrict__ Mstat, const float* __restrict__ Lstat,
    half_t* __restrict__ O16)
{
    __shared__ alignas(16) half_t As[2][128 * 32];
    __shared__ alignas(16) half_t Bs[2][128 * 32];
    __shared__ float scaleS[8][128];
    __shared__ float invS[128];

    const int t    = threadIdx.x;
    const int lane = t & 63;
    const int wm   = t >> 6;        // 0..3: wave's 32-row m-group
    const int lanen = lane & 15;
    const int quad  = lane >> 4;
    const int sl    = quad ^ ((lanen >> 1) & 3);

    int bx, by, z;
    if (SWZ) {
        const int wgid = blockIdx.x;
        const int c    = wgid & 7;        // XCD
        const int tmp  = wgid >> 3;
        const int tile = tmp & 31;        // 32 tiles (8m x 4h) per batch
        z  = c + 8 * (tmp >> 5);
        bx = tile & 7;
        by = tile >> 3;
    } else {
        bx = blockIdx.x; by = blockIdx.y; z = blockIdx.z;
    }
    const long m0 = (long)bx * 128;
    const long h0 = (long)by * 128;

    // prologue: merge per-col-block stats for this block's 128 rows
    if (t < 128) {
        float mv[8];
        float M = -1e30f;
#pragma unroll
        for (int kb = 0; kb < 8; kb++) {
            mv[kb] = Mstat[((long)z * 8 + kb) * SEQ + m0 + t];
            M = fmaxf(M, mv[kb]);
        }
        float ls = 0.f;
#pragma unroll
        for (int kb = 0; kb < 8; kb++) {
            float sc = __expf(mv[kb] - M);
            scaleS[kb][t] = sc;
            ls += Lstat[((long)z * 8 + kb) * SEQ + m0 + t] * sc;
        }
        invS[t] = 1.f / ls;
    }
    __syncthreads();

    const half_t* Ab = E  + (long)z * SEQ * SEQ;
    const half_t* Bb = vT + (long)z * HID * SEQ;

    f32x4 acc[2][8];
#pragma unroll
    for (int i = 0; i < 2; i++)
#pragma unroll
        for (int j = 0; j < 8; j++)
            acc[i][j] = f32x4{0.f, 0.f, 0.f, 0.f};

    // A (E): 512 chunks (2/thread); B (vT): 512 chunks (2/thread); T2 pre-swizzled source
    const half_t* gA[2]; int lA[2];
    const half_t* gB[2]; int lB[2];
#pragma unroll
    for (int s = 0; s < 2; s++) {
        int c = t + 256 * s;
        gA[s] = Ab + (m0 + (c >> 2)) * SEQ + ((c & 3) ^ ((c >> 3) & 3)) * 8;
        gB[s] = Bb + (h0 + (c >> 2)) * SEQ + ((c & 3) ^ ((c >> 3) & 3)) * 8;
        lA[s] = c * 8;
        lB[s] = c * 8;
    }

    int aoff[2], boff[8];
#pragma unroll
    for (int i = 0; i < 2; i++) aoff[i] = (wm * 32 + i * 16 + lanen) * 32 + sl * 8;
#pragma unroll
    for (int j = 0; j < 8; j++) boff[j] = (j * 16 + lanen) * 32 + sl * 8;

    for (int k0 = 0; k0 < SEQ; k0 += 64) {
#pragma unroll
        for (int sub = 0; sub < 2; sub++) {
            const int ks = k0 + sub * 32;
#pragma unroll
            for (int s = 0; s < 2; s++) {
                __builtin_amdgcn_global_load_lds((gas_ptr)(gA[s] + ks), (las_ptr)&As[sub][lA[s]], 16, 0, 0);
                __builtin_amdgcn_global_load_lds((gas_ptr)(gB[s] + ks), (las_ptr)&Bs[sub][lB[s]], 16, 0, 0);
            }
        }
        __syncthreads();

        const int kb = k0 >> 7;   // both 32-wide subs lie in the same 128-col stats block
#pragma unroll
        for (int sub = 0; sub < 2; sub++) {
            half8 af0 = *(const half8*)&As[sub][aoff[0]];
            half8 af1 = *(const half8*)&As[sub][aoff[1]];
            // per-row rescale exp(m_kb - M); A-operand row = lane&15 within 16-block
            af0 *= (half_t)scaleS[kb][wm * 32 + 0 * 16 + lanen];
            af1 *= (half_t)scaleS[kb][wm * 32 + 1 * 16 + lanen];
#pragma unroll
            for (int j = 0; j < 8; j++) {
                half8 bf = *(const half8*)&Bs[sub][boff[j]];
                acc[0][j] = __builtin_amdgcn_mfma_f32_16x16x32_f16(af0, bf, acc[0][j], 0, 0, 0);
                acc[1][j] = __builtin_amdgcn_mfma_f32_16x16x32_f16(af1, bf, acc[1][j], 0, 0, 0);
            }
        }
        __syncthreads();
    }

    half_t* o = O16 + (long)z * SEQ * HID;
#pragma unroll
    for (int i = 0; i < 2; i++) {
        long mrow = m0 + wm * 32 + i * 16 + quad * 4;
        int rl = wm * 32 + i * 16 + quad * 4;
#pragma unroll
        for (int j = 0; j < 8; j++) {
            long gn = h0 + j * 16 + lanen;
#pragma unroll
            for (int r = 0; r < 4; r++)
                o[(mrow + r) * HID + gn] = (half_t)(acc[i][j][r] * invS[rl + r]);
        }
    }
}

// ---------------- host ----------------
extern "C" void kernel_launch(void* const* d_in, const int* in_sizes, int n_in,
                              void* d_out, int out_size, void* d_ws, size_t ws_size,
                              hipStream_t stream) {
    const float* h  = (const float*)d_in[0];
    const float* Wv = (const float*)d_in[1];
    const float* bv = (const float*)d_in[2];
    const float* Wk = (const float*)d_in[3];
    const float* bk = (const float*)d_in[4];
    const float* Wq = (const float*)d_in[5];
    const float* bq = (const float*)d_in[6];
    const float* Wo = (const float*)d_in[7];
    const float* bo = (const float*)d_in[8];

    uint8_t* ws = (uint8_t*)d_ws;
    size_t off = 0;
    auto alloc = [&](size_t bytes) { size_t o = off; off += (bytes + 255) & ~(size_t)255; return o; };

    half_t* W16   = (half_t*)(ws + alloc((size_t)3 * HID * DIN * 2)); // [Wv][Wk][Wq]
    half_t* Wo16  = (half_t*)(ws + alloc((size_t)DIN * HID * 2));
    float*  biasq = (float*)(ws + alloc((size_t)3 * HID * 4));        // [bv][bk][bq]
    half_t* k16   = (half_t*)(ws + alloc((size_t)MTOT * HID * 2));
    half_t* q16   = (half_t*)(ws + alloc((size_t)MTOT * HID * 2));    // reused as O16 per group
    half_t* vT    = (half_t*)(ws + alloc((size_t)MTOT * HID * 2));    // [b][h][m]
    size_t h16_off = alloc((size_t)MTOT * DIN * 2);
    half_t* h16   = (half_t*)(ws + h16_off);
    half_t* O16 = q16;  // q dead after its group's se_k; O written strictly after

    // E + stats overlap the (dead-after-K1) h16 region onward
    size_t s_avail = ws_size > h16_off ? ws_size - h16_off : 0;
    size_t per_batch = (size_t)SEQ * SEQ * 2 + 2 * 8 * SEQ * 4;
    int GB = (int)(s_avail / per_batch);
    if (GB < 1)  GB = 1;
    if (GB > NB) GB = NB;
    half_t* Ebuf  = (half_t*)(ws + h16_off);
    float*  Mstat = (float*)(ws + h16_off + (size_t)GB * SEQ * SEQ * 2);
    float*  Lstat = Mstat + (size_t)GB * 8 * SEQ;

    // K0: conversions
    cvt_kernel<<<dim3((MTOT * DIN / 4 + 255) / 256), 256, 0, stream>>>(h, h16, MTOT * DIN / 4);
    cvt4_kernel<<<dim3((HID * DIN / 4 + 255) / 256, 4), 256, 0, stream>>>(
        Wv, Wk, Wq, Wo, W16, W16 + HID * DIN, W16 + 2 * HID * DIN, Wo16, HID * DIN / 4);
    pack_bias<<<dim3(1), 512, 0, stream>>>(bv, bk, bq, biasq);

    // K1: QKV projections (z: 0=V->vT, 1=K, 2=Q)
    gemm_k<0><<<dim3(MTOT / 128, HID / 128, 3), 256, 0, stream>>>(
        h16, DIN, 0,
        W16, DIN, (long)HID * DIN,
        (void*)k16, HID, (long)MTOT * HID,
        biasq, DIN, vT);

    if (GB == NB) {
        // XCD-pinned path: each batch's tiles land on XCD z%8 -> Q/K (se) and E/vT (pv)
        // are L2-resident per batch; staging re-reads become L2 hits.
        se_k<1><<<dim3(NB * 64), 256, 0, stream>>>(q16, k16, Ebuf, Mstat, Lstat);
        pv_k<1><<<dim3(NB * 32), 256, 0, stream>>>(Ebuf, vT, Mstat, Lstat, O16);
    } else {
        for (int g0 = 0; g0 < NB; g0 += GB) {
            int gb = NB - g0 < GB ? NB - g0 : GB;
            se_k<0><<<dim3(SEQ / 128, SEQ / 128, gb), 256, 0, stream>>>(
                q16 + (size_t)g0 * SEQ * HID,
                k16 + (size_t)g0 * SEQ * HID,
                Ebuf, Mstat, Lstat);
            pv_k<0><<<dim3(SEQ / 128, HID / 128, gb), 256, 0, stream>>>(
                Ebuf, vT + (size_t)g0 * HID * SEQ,
                Mstat, Lstat,
                O16 + (size_t)g0 * SEQ * HID);
        }
    }

    // K5: out = relu(O Wo^T + bo)  (f32 out)
    gemm_k<3><<<dim3(MTOT / 128, DIN / 128, 1), 256, 0, stream>>>(
        O16, HID, 0,
        Wo16, HID, 0,
        d_out, DIN, 0,
        bo, HID, nullptr);

    (void)in_sizes; (void)n_in; (void)out_size;
}

// Round 13
// 247.158 us; speedup vs baseline: 1.0885x; 1.0885x over previous
//
#include <hip/hip_runtime.h>
#include <cstdint>
#include <cstddef>

#define NB    32          // batches
#define SEQ   1024        // sequence length
#define DIN   256
#define HID   512
#define MTOT  32768       // NB*SEQ

typedef _Float16 half_t;
typedef _Float16 half8  __attribute__((ext_vector_type(8)));
typedef _Float16 half4v __attribute__((ext_vector_type(4)));
typedef float    f32x4  __attribute__((ext_vector_type(4)));

typedef __attribute__((address_space(1))) const void* gas_ptr;
typedef __attribute__((address_space(3))) void*       las_ptr;

// Register model (r8/r10/r11): reported VGPR_Count excludes MFMA accumulators;
// unified budget/wave = 512 / (waves per SIMD). acc[2][8]=64-reg tiles fit (256,3).
// T2 swizzle: on pv_k/gemm_k (conflicts->0); NOT on se_k (permuted source broke
// run-length coalescing in its L2-request-bound staging: r9 A/B 72.7 vs 55.3).
// T1 XCD pinning: se_k/pv_k (r7: FETCH 147->33 MB, -11us); r13 extends it to
// gemm_k (h16 re-fetched 2.5x on the default grid: FETCH 41 MB vs 17 ideal).

// ---------------- f32 -> f16 convert ----------------
__global__ void cvt_kernel(const float* __restrict__ src, half_t* __restrict__ dst, int n4) {
    int i = blockIdx.x * blockDim.x + threadIdx.x;
    if (i < n4) {
        f32x4 v = ((const f32x4*)src)[i];
        half4v h;
        h[0] = (half_t)v[0]; h[1] = (half_t)v[1]; h[2] = (half_t)v[2]; h[3] = (half_t)v[3];
        ((half4v*)dst)[i] = h;
    }
}

// all 4 weight matrices are HID*DIN == DIN*HID elements; blockIdx.y selects
__global__ void cvt4_kernel(const float* __restrict__ s0, const float* __restrict__ s1,
                            const float* __restrict__ s2, const float* __restrict__ s3,
                            half_t* __restrict__ d0, half_t* __restrict__ d1,
                            half_t* __restrict__ d2, half_t* __restrict__ d3, int n4) {
    int y = blockIdx.y;
    const float* s = y == 0 ? s0 : y == 1 ? s1 : y == 2 ? s2 : s3;
    half_t*      d = y == 0 ? d0 : y == 1 ? d1 : y == 2 ? d2 : d3;
    int i = blockIdx.x * blockDim.x + threadIdx.x;
    if (i < n4) {
        f32x4 v = ((const f32x4*)s)[i];
        half4v h;
        h[0] = (half_t)v[0]; h[1] = (half_t)v[1]; h[2] = (half_t)v[2]; h[3] = (half_t)v[3];
        ((half4v*)d)[i] = h;
    }
}

__global__ void pack_bias(const float* __restrict__ bv, const float* __restrict__ bk,
                          const float* __restrict__ bq, float* __restrict__ dst) {
    int t = threadIdx.x;
    if (t < HID) {
        dst[t]         = bv[t];
        dst[HID + t]   = bk[t];
        dst[2*HID + t] = bq[t];
    }
}

// ---------------- generic GEMM (projections), 128x128 tile ----------------
// C[m][n] = sum_k A[m][k] * B[n][k]
// K-loop unrolled x2 (two 32-wide sub-buffers, one sync pair per 64-wide step).
// T2 swizzle: source kchunk ^((c>>3)&3), read slot quad^((lanen>>1)&3).
// T1 grid swizzle (NY=n-tiles, NZ=z-count): wgid = xcd + 8*(mloc*(NY*NZ) + rr)
// -> XCD c owns m-tiles [c*32, c*32+32) (A-slice 2 MB, L2-resident); the NY*NZ
// variants of one m-tile dispatch consecutively so the A-tile stays L2-hot.
// MODE 0: QKV proj. bias+relu, f16 out. z=0 -> transposed into out2 (vT[b][h][m]); z=1,2 -> row-major.
// MODE 3: out proj. f32 out, bias+relu.
template<int MODE, int NY, int NZ>
__global__ __launch_bounds__(256, 3) void gemm_k(
    const half_t* __restrict__ A, long lda, long a_bs,
    const half_t* __restrict__ Bw, long ldb, long b_bs,
    void* __restrict__ Out, long ldo, long o_bs,
    const float* __restrict__ bias,
    int Kdim, half_t* __restrict__ out2)
{
    __shared__ alignas(16) half_t As[2][128 * 32];
    __shared__ alignas(16) half_t Bs[2][128 * 32];

    const int t    = threadIdx.x;
    const int lane = t & 63;
    const int wave = t >> 6;
    const int wm   = wave >> 1;
    const int wn   = wave & 1;
    const int lanen = lane & 15;
    const int quad  = lane >> 4;
    const int sl    = quad ^ ((lanen >> 1) & 3);   // swizzled read slot

    // T1 decode: XCD-pinned m-panels
    const int wgid  = blockIdx.x;
    const int c     = wgid & 7;
    const int inner = wgid >> 3;
    constexpr int REST = NY * NZ;
    const int mloc = inner / REST;
    const int rr   = inner - mloc * REST;
    const int z    = rr / NY;
    const int byy  = rr - z * NY;
    const long m0 = (long)(c * 32 + mloc) * 128;
    const long n0 = (long)byy * 128;

    const half_t* Ab = A  + (long)z * a_bs;
    const half_t* Bb = Bw + (long)z * b_bs;

    f32x4 acc[4][4];
#pragma unroll
    for (int i = 0; i < 4; i++)
#pragma unroll
        for (int j = 0; j < 4; j++)
            acc[i][j] = f32x4{0.f, 0.f, 0.f, 0.f};

    const int c0 = t, c1 = t + 256;
    const int r0 = c0 >> 2, kc0 = (c0 & 3) ^ ((c0 >> 3) & 3);   // pre-swizzled source slot
    const int r1 = c1 >> 2, kc1 = (c1 & 3) ^ ((c1 >> 3) & 3);

    const half_t* gA0 = Ab + (m0 + r0) * lda + kc0 * 8;
    const half_t* gA1 = Ab + (m0 + r1) * lda + kc1 * 8;
    const half_t* gB0 = Bb + (n0 + r0) * ldb + kc0 * 8;
    const half_t* gB1 = Bb + (n0 + r1) * ldb + kc1 * 8;
    const int lA0 = c0 * 8, lA1 = c1 * 8;
    const int lB0 = c0 * 8, lB1 = c1 * 8;

    int aoff[4], boff[4];
#pragma unroll
    for (int i = 0; i < 4; i++) aoff[i] = (wm * 64 + i * 16 + lanen) * 32 + sl * 8;
#pragma unroll
    for (int j = 0; j < 4; j++) boff[j] = (wn * 64 + j * 16 + lanen) * 32 + sl * 8;

    for (int k0 = 0; k0 < Kdim; k0 += 64) {
#pragma unroll
        for (int sub = 0; sub < 2; sub++) {
            const int ks = k0 + sub * 32;
            __builtin_amdgcn_global_load_lds((gas_ptr)(gA0 + ks), (las_ptr)&As[sub][lA0], 16, 0, 0);
            __builtin_amdgcn_global_load_lds((gas_ptr)(gA1 + ks), (las_ptr)&As[sub][lA1], 16, 0, 0);
            __builtin_amdgcn_global_load_lds((gas_ptr)(gB0 + ks), (las_ptr)&Bs[sub][lB0], 16, 0, 0);
            __builtin_amdgcn_global_load_lds((gas_ptr)(gB1 + ks), (las_ptr)&Bs[sub][lB1], 16, 0, 0);
        }
        __syncthreads();

        {
            half8 af[4], bf[4];
#pragma unroll
            for (int i = 0; i < 4; i++) af[i] = *(const half8*)&As[0][aoff[i]];
#pragma unroll
            for (int j = 0; j < 4; j++) bf[j] = *(const half8*)&Bs[0][boff[j]];
#pragma unroll
            for (int i = 0; i < 4; i++)
#pragma unroll
                for (int j = 0; j < 4; j++)
                    acc[i][j] = __builtin_amdgcn_mfma_f32_16x16x32_f16(af[i], bf[j], acc[i][j], 0, 0, 0);
        }
        {
            half8 af[4], bf[4];
#pragma unroll
            for (int i = 0; i < 4; i++) af[i] = *(const half8*)&As[1][aoff[i]];
#pragma unroll
            for (int j = 0; j < 4; j++) bf[j] = *(const half8*)&Bs[1][boff[j]];
#pragma unroll
            for (int i = 0; i < 4; i++)
#pragma unroll
                for (int j = 0; j < 4; j++)
                    acc[i][j] = __builtin_amdgcn_mfma_f32_16x16x32_f16(af[i], bf[j], acc[i][j], 0, 0, 0);
        }
        __syncthreads();
    }

    // C/D layout: col = lane&15, row = quad*4 + reg
#pragma unroll
    for (int i = 0; i < 4; i++) {
        long mrow = m0 + wm * 64 + i * 16 + quad * 4;
#pragma unroll
        for (int j = 0; j < 4; j++) {
            long gn = n0 + wn * 64 + j * 16 + lanen;
            f32x4 v = acc[i][j];
            if (MODE == 0) {
                float bb = bias[z * HID + gn];
                half_t h0 = (half_t)fmaxf(v[0] + bb, 0.f);
                half_t h1 = (half_t)fmaxf(v[1] + bb, 0.f);
                half_t h2 = (half_t)fmaxf(v[2] + bb, 0.f);
                half_t h3 = (half_t)fmaxf(v[3] + bb, 0.f);
                if (z == 0) {
                    long bidx = mrow >> 10;
                    long pos  = mrow & 1023;
                    half4v pk; pk[0] = h0; pk[1] = h1; pk[2] = h2; pk[3] = h3;
                    *(half4v*)(out2 + ((bidx * HID + gn) << 10) + pos) = pk;
                } else {
                    half_t* o = (half_t*)Out + (long)(z - 1) * o_bs;
                    o[(mrow + 0) * ldo + gn] = h0;
                    o[(mrow + 1) * ldo + gn] = h1;
                    o[(mrow + 2) * ldo + gn] = h2;
                    o[(mrow + 3) * ldo + gn] = h3;
                }
            } else {
                float* o = (float*)Out;
                float bb = bias[gn];
#pragma unroll
                for (int r = 0; r < 4; r++) o[(mrow + r) * ldo + gn] = fmaxf(v[r] + bb, 0.f);
            }
        }
    }
}

// ---------------- S = q k^T with fused exp, 128x128 tile, 4 M-split waves ----------------
// Each wave owns 32 m-rows x ALL 128 n-cols (acc[2][8] = 64 acc-regs) -> (256,3),
// 3 blocks/CU. n-tile == stats block -> per-wave stats, kb = by. Linear staging
// source (no T2: r9). SWZ=1: batch pinned to XCD (L2-resident Q/K).
template<int SWZ>
__global__ __launch_bounds__(256, 3) void se_k(
    const half_t* __restrict__ Q, const half_t* __restrict__ K,
    half_t* __restrict__ E, float* __restrict__ Mstat, float* __restrict__ Lstat)
{
    __shared__ alignas(16) half_t As[2][128 * 32];
    __shared__ alignas(16) half_t Bs[2][128 * 32];

    const int t    = threadIdx.x;
    const int lane = t & 63;
    const int wm   = t >> 6;        // 0..3: wave's 32-row m-group
    const int lanen = lane & 15;
    const int quad  = lane >> 4;

    int bx, by, z;
    if (SWZ) {
        const int wgid = blockIdx.x;
        const int c    = wgid & 7;        // XCD
        const int tmp  = wgid >> 3;
        const int tile = tmp & 63;        // 64 tiles (8m x 8n) per batch
        z  = c + 8 * (tmp >> 6);
        bx = tile & 7;
        by = tile >> 3;
    } else {
        bx = blockIdx.x; by = blockIdx.y; z = blockIdx.z;
    }
    const long m0 = (long)bx * 128;
    const long n0 = (long)by * 128;

    const half_t* Ab = Q + (long)z * SEQ * HID;
    const half_t* Bb = K + (long)z * SEQ * HID;

    f32x4 acc[2][8];
#pragma unroll
    for (int i = 0; i < 2; i++)
#pragma unroll
        for (int j = 0; j < 8; j++)
            acc[i][j] = f32x4{0.f, 0.f, 0.f, 0.f};

    // A: 512 chunks (2/thread), B: 512 chunks (2/thread); chunk c -> row c>>2, kchunk c&3
    const half_t* gA[2]; int lA[2];
    const half_t* gB[2]; int lB[2];
#pragma unroll
    for (int s = 0; s < 2; s++) {
        int c = t + 256 * s;
        gA[s] = Ab + (m0 + (c >> 2)) * HID + (c & 3) * 8;
        gB[s] = Bb + (n0 + (c >> 2)) * HID + (c & 3) * 8;
        lA[s] = c * 8;
        lB[s] = c * 8;
    }

    int aoff[2], boff[8];
#pragma unroll
    for (int i = 0; i < 2; i++) aoff[i] = (wm * 32 + i * 16 + lanen) * 32 + quad * 8;
#pragma unroll
    for (int j = 0; j < 8; j++) boff[j] = (j * 16 + lanen) * 32 + quad * 8;

    for (int k0 = 0; k0 < HID; k0 += 64) {
#pragma unroll
        for (int sub = 0; sub < 2; sub++) {
            const int ks = k0 + sub * 32;
#pragma unroll
            for (int s = 0; s < 2; s++) {
                __builtin_amdgcn_global_load_lds((gas_ptr)(gA[s] + ks), (las_ptr)&As[sub][lA[s]], 16, 0, 0);
                __builtin_amdgcn_global_load_lds((gas_ptr)(gB[s] + ks), (las_ptr)&Bs[sub][lB[s]], 16, 0, 0);
            }
        }
        __syncthreads();

#pragma unroll
        for (int sub = 0; sub < 2; sub++) {
            half8 af0 = *(const half8*)&As[sub][aoff[0]];
            half8 af1 = *(const half8*)&As[sub][aoff[1]];
#pragma unroll
            for (int j = 0; j < 8; j++) {
                half8 bf = *(const half8*)&Bs[sub][boff[j]];
                acc[0][j] = __builtin_amdgcn_mfma_f32_16x16x32_f16(af0, bf, acc[0][j], 0, 0, 0);
                acc[1][j] = __builtin_amdgcn_mfma_f32_16x16x32_f16(af1, bf, acc[1][j], 0, 0, 0);
            }
        }
        __syncthreads();
    }

    // ---- epilogue: per-wave row max over the full 128-col stats block ----
    float mf[2][4];
#pragma unroll
    for (int i = 0; i < 2; i++)
#pragma unroll
        for (int r = 0; r < 4; r++) {
            float v = acc[i][0][r];
#pragma unroll
            for (int j = 1; j < 8; j++) v = fmaxf(v, acc[i][j][r]);
#pragma unroll
            for (int off = 8; off > 0; off >>= 1)
                v = fmaxf(v, __shfl_xor(v, off, 64));
            mf[i][r] = v;
        }

    // ---- exp + row partial sums + E store ----
    half_t* Eb = E + (long)z * SEQ * SEQ;
    float rs[2][4];
#pragma unroll
    for (int i = 0; i < 2; i++)
#pragma unroll
        for (int r = 0; r < 4; r++) rs[i][r] = 0.f;
#pragma unroll
    for (int i = 0; i < 2; i++) {
        long mrow = m0 + wm * 32 + i * 16 + quad * 4;
#pragma unroll
        for (int j = 0; j < 8; j++) {
            long gn = n0 + j * 16 + lanen;
#pragma unroll
            for (int r = 0; r < 4; r++) {
                float e = __expf(acc[i][j][r] - mf[i][r]);
                rs[i][r] += e;
                Eb[(mrow + r) * SEQ + gn] = (half_t)e;
            }
        }
    }
#pragma unroll
    for (int i = 0; i < 2; i++)
#pragma unroll
        for (int r = 0; r < 4; r++) {
            float v = rs[i][r];
#pragma unroll
            for (int off = 8; off > 0; off >>= 1)
                v += __shfl_xor(v, off, 64);
            rs[i][r] = v;
        }

    // stats: kb = by (n-tile == stats block); rows are wave-private -> no conflicts
    if (lanen == 0) {
        long base = ((long)z * 8 + by) * SEQ + m0 + wm * 32;
#pragma unroll
        for (int i = 0; i < 2; i++)
#pragma unroll
            for (int r = 0; r < 4; r++) {
                Mstat[base + i * 16 + quad * 4 + r] = mf[i][r];
                Lstat[base + i * 16 + quad * 4 + r] = rs[i][r];
            }
    }
}

// ---------------- O = P vT, 128x128 tile, 4 M-split waves ----------------
// Each wave owns 32 m-rows x ALL 128 h-cols (acc[2][8] = 64 acc-regs) -> (256,3).
// T2 swizzle kept. SWZ=1: batch pinned to XCD (E+vT L2-resident).
template<int SWZ>
__global__ __launch_bounds__(256, 3) void pv_k(
    const half_t* __restrict__ E, const half_t* __restrict__ vT,
    const float* __restrict__ Mstat, const float* __restrict__ Lstat,
    half_t* __restrict__ O16)
{
    __shared__ alignas(16) half_t As[2][128 * 32];
    __shared__ alignas(16) half_t Bs[2][128 * 32];
    __shared__ float scaleS[8][128];
    __shared__ float invS[128];

    const int t    = threadIdx.x;
    const int lane = t & 63;
    const int wm   = t >> 6;        // 0..3: wave's 32-row m-group
    const int lanen = lane & 15;
    const int quad  = lane >> 4;
    const int sl    = quad ^ ((lanen >> 1) & 3);

    int bx, by, z;
    if (SWZ) {
        const int wgid = blockIdx.x;
        const int c    = wgid & 7;        // XCD
        const int tmp  = wgid >> 3;
        const int tile = tmp & 31;        // 32 tiles (8m x 4h) per batch
        z  = c + 8 * (tmp >> 5);
        bx = tile & 7;
        by = tile >> 3;
    } else {
        bx = blockIdx.x; by = blockIdx.y; z = blockIdx.z;
    }
    const long m0 = (long)bx * 128;
    const long h0 = (long)by * 128;

    // prologue: merge per-col-block stats for this block's 128 rows
    if (t < 128) {
        float mv[8];
        float M = -1e30f;
#pragma unroll
        for (int kb = 0; kb < 8; kb++) {
            mv[kb] = Mstat[((long)z * 8 + kb) * SEQ + m0 + t];
            M = fmaxf(M, mv[kb]);
        }
        float ls = 0.f;
#pragma unroll
        for (int kb = 0; kb < 8; kb++) {
            float sc = __expf(mv[kb] - M);
            scaleS[kb][t] = sc;
            ls += Lstat[((long)z * 8 + kb) * SEQ + m0 + t] * sc;
        }
        invS[t] = 1.f / ls;
    }
    __syncthreads();

    const half_t* Ab = E  + (long)z * SEQ * SEQ;
    const half_t* Bb = vT + (long)z * HID * SEQ;

    f32x4 acc[2][8];
#pragma unroll
    for (int i = 0; i < 2; i++)
#pragma unroll
        for (int j = 0; j < 8; j++)
            acc[i][j] = f32x4{0.f, 0.f, 0.f, 0.f};

    // A (E): 512 chunks (2/thread); B (vT): 512 chunks (2/thread); T2 pre-swizzled source
    const half_t* gA[2]; int lA[2];
    const half_t* gB[2]; int lB[2];
#pragma unroll
    for (int s = 0; s < 2; s++) {
        int c = t + 256 * s;
        gA[s] = Ab + (m0 + (c >> 2)) * SEQ + ((c & 3) ^ ((c >> 3) & 3)) * 8;
        gB[s] = Bb + (h0 + (c >> 2)) * SEQ + ((c & 3) ^ ((c >> 3) & 3)) * 8;
        lA[s] = c * 8;
        lB[s] = c * 8;
    }

    int aoff[2], boff[8];
#pragma unroll
    for (int i = 0; i < 2; i++) aoff[i] = (wm * 32 + i * 16 + lanen) * 32 + sl * 8;
#pragma unroll
    for (int j = 0; j < 8; j++) boff[j] = (j * 16 + lanen) * 32 + sl * 8;

    for (int k0 = 0; k0 < SEQ; k0 += 64) {
#pragma unroll
        for (int sub = 0; sub < 2; sub++) {
            const int ks = k0 + sub * 32;
#pragma unroll
            for (int s = 0; s < 2; s++) {
                __builtin_amdgcn_global_load_lds((gas_ptr)(gA[s] + ks), (las_ptr)&As[sub][lA[s]], 16, 0, 0);
                __builtin_amdgcn_global_load_lds((gas_ptr)(gB[s] + ks), (las_ptr)&Bs[sub][lB[s]], 16, 0, 0);
            }
        }
        __syncthreads();

        const int kb = k0 >> 7;   // both 32-wide subs lie in the same 128-col stats block
#pragma unroll
        for (int sub = 0; sub < 2; sub++) {
            half8 af0 = *(const half8*)&As[sub][aoff[0]];
            half8 af1 = *(const half8*)&As[sub][aoff[1]];
            // per-row rescale exp(m_kb - M); A-operand row = lane&15 within 16-block
            af0 *= (half_t)scaleS[kb][wm * 32 + 0 * 16 + lanen];
            af1 *= (half_t)scaleS[kb][wm * 32 + 1 * 16 + lanen];
#pragma unroll
            for (int j = 0; j < 8; j++) {
                half8 bf = *(const half8*)&Bs[sub][boff[j]];
                acc[0][j] = __builtin_amdgcn_mfma_f32_16x16x32_f16(af0, bf, acc[0][j], 0, 0, 0);
                acc[1][j] = __builtin_amdgcn_mfma_f32_16x16x32_f16(af1, bf, acc[1][j], 0, 0, 0);
            }
        }
        __syncthreads();
    }

    half_t* o = O16 + (long)z * SEQ * HID;
#pragma unroll
    for (int i = 0; i < 2; i++) {
        long mrow = m0 + wm * 32 + i * 16 + quad * 4;
        int rl = wm * 32 + i * 16 + quad * 4;
#pragma unroll
        for (int j = 0; j < 8; j++) {
            long gn = h0 + j * 16 + lanen;
#pragma unroll
            for (int r = 0; r < 4; r++)
                o[(mrow + r) * HID + gn] = (half_t)(acc[i][j][r] * invS[rl + r]);
        }
    }
}

// ---------------- host ----------------
extern "C" void kernel_launch(void* const* d_in, const int* in_sizes, int n_in,
                              void* d_out, int out_size, void* d_ws, size_t ws_size,
                              hipStream_t stream) {
    const float* h  = (const float*)d_in[0];
    const float* Wv = (const float*)d_in[1];
    const float* bv = (const float*)d_in[2];
    const float* Wk = (const float*)d_in[3];
    const float* bk = (const float*)d_in[4];
    const float* Wq = (const float*)d_in[5];
    const float* bq = (const float*)d_in[6];
    const float* Wo = (const float*)d_in[7];
    const float* bo = (const float*)d_in[8];

    uint8_t* ws = (uint8_t*)d_ws;
    size_t off = 0;
    auto alloc = [&](size_t bytes) { size_t o = off; off += (bytes + 255) & ~(size_t)255; return o; };

    half_t* W16   = (half_t*)(ws + alloc((size_t)3 * HID * DIN * 2)); // [Wv][Wk][Wq]
    half_t* Wo16  = (half_t*)(ws + alloc((size_t)DIN * HID * 2));
    float*  biasq = (float*)(ws + alloc((size_t)3 * HID * 4));        // [bv][bk][bq]
    half_t* k16   = (half_t*)(ws + alloc((size_t)MTOT * HID * 2));
    half_t* q16   = (half_t*)(ws + alloc((size_t)MTOT * HID * 2));    // reused as O16 per group
    half_t* vT    = (half_t*)(ws + alloc((size_t)MTOT * HID * 2));    // [b][h][m]
    size_t h16_off = alloc((size_t)MTOT * DIN * 2);
    half_t* h16   = (half_t*)(ws + h16_off);
    half_t* O16 = q16;  // q dead after its group's se_k; O written strictly after

    // E + stats overlap the (dead-after-K1) h16 region onward
    size_t s_avail = ws_size > h16_off ? ws_size - h16_off : 0;
    size_t per_batch = (size_t)SEQ * SEQ * 2 + 2 * 8 * SEQ * 4;
    int GB = (int)(s_avail / per_batch);
    if (GB < 1)  GB = 1;
    if (GB > NB) GB = NB;
    half_t* Ebuf  = (half_t*)(ws + h16_off);
    float*  Mstat = (float*)(ws + h16_off + (size_t)GB * SEQ * SEQ * 2);
    float*  Lstat = Mstat + (size_t)GB * 8 * SEQ;

    // K0: conversions
    cvt_kernel<<<dim3((MTOT * DIN / 4 + 255) / 256), 256, 0, stream>>>(h, h16, MTOT * DIN / 4);
    cvt4_kernel<<<dim3((HID * DIN / 4 + 255) / 256, 4), 256, 0, stream>>>(
        Wv, Wk, Wq, Wo, W16, W16 + HID * DIN, W16 + 2 * HID * DIN, Wo16, HID * DIN / 4);
    pack_bias<<<dim3(1), 512, 0, stream>>>(bv, bk, bq, biasq);

    // K1: QKV projections (z: 0=V->vT, 1=K, 2=Q); T1 XCD-pinned 1-D grid:
    // 8 XCDs x 32 m-tiles x (4 n-tiles x 3 z) = 3072 blocks
    gemm_k<0, 4, 3><<<dim3(8 * 32 * 12), 256, 0, stream>>>(
        h16, DIN, 0,
        W16, DIN, (long)HID * DIN,
        (void*)k16, HID, (long)MTOT * HID,
        biasq, DIN, vT);

    if (GB == NB) {
        // XCD-pinned path: each batch's tiles land on XCD z%8 -> Q/K (se) and E/vT (pv)
        // are L2-resident per batch; staging re-reads become L2 hits.
        se_k<1><<<dim3(NB * 64), 256, 0, stream>>>(q16, k16, Ebuf, Mstat, Lstat);
        pv_k<1><<<dim3(NB * 32), 256, 0, stream>>>(Ebuf, vT, Mstat, Lstat, O16);
    } else {
        for (int g0 = 0; g0 < NB; g0 += GB) {
            int gb = NB - g0 < GB ? NB - g0 : GB;
            se_k<0><<<dim3(SEQ / 128, SEQ / 128, gb), 256, 0, stream>>>(
                q16 + (size_t)g0 * SEQ * HID,
                k16 + (size_t)g0 * SEQ * HID,
                Ebuf, Mstat, Lstat);
            pv_k<0><<<dim3(SEQ / 128, HID / 128, gb), 256, 0, stream>>>(
                Ebuf, vT + (size_t)g0 * HID * SEQ,
                Mstat, Lstat,
                O16 + (size_t)g0 * SEQ * HID);
        }
    }

    // K5: out = relu(O Wo^T + bo); T1 XCD-pinned: 8 x 32 x (2 n-tiles) = 512 blocks
    gemm_k<3, 2, 1><<<dim3(8 * 32 * 2), 256, 0, stream>>>(
        O16, HID, 0,
        Wo16, HID, 0,
        d_out, DIN, 0,
        bo, HID, nullptr);

    (void)in_sizes; (void)n_in; (void)out_size;
}